// Round 1
// baseline (292.062 us; speedup 1.0000x reference)
//
#include <hip/hip_runtime.h>
#include <hip/hip_bf16.h>

#define EPSV 1e-5f
#define DW_THR 4.0f
#define PW_THR 1e-3f

static constexpr int BB = 32, CIN = 256, COUT = 512, HH = 56, WW = 56, HW = HH * WW; // 3136
static constexpr int OT = 8; // output channels per block in pointwise stage

// ---------------- Stage 1: depthwise 3x3 + bias + BN1 + ReLU + prune decision ----------------
__global__ __launch_bounds__(256) void dw_kernel(
    const float* __restrict__ x, const float* __restrict__ dw_w, const float* __restrict__ dw_b,
    const float* __restrict__ g1, const float* __restrict__ b1,
    const float* __restrict__ m1, const float* __restrict__ v1,
    __hip_bfloat16* __restrict__ y, int* __restrict__ flags)
{
    const int blk = blockIdx.x;          // b*CIN + c
    const int c   = blk & (CIN - 1);
    const int tid = threadIdx.x;

    __shared__ float xs[58 * 58];        // 56x56 + halo of zeros
    const float* xp = x + (size_t)blk * HW;
    for (int i = tid; i < 58 * 58; i += 256) {
        int r = i / 58, q = i - r * 58;
        int ih = r - 1, iw = q - 1;
        float v = 0.f;
        if ((unsigned)ih < 56u && (unsigned)iw < 56u) v = xp[ih * WW + iw];
        xs[i] = v;
    }

    float w[9];
#pragma unroll
    for (int k = 0; k < 9; k++) w[k] = dw_w[c * 9 + k];
    const float inv = g1[c] * rsqrtf(v1[c] + EPSV);
    const float sh  = (dw_b[c] - m1[c]) * inv + b1[c];
    __syncthreads();

    float vals[13];
    float mx = 0.f;
#pragma unroll
    for (int k = 0; k < 13; k++) {
        int p = tid + k * 256;
        if (p < HW) {
            int oh = p / WW, ow = p - oh * WW;
            const float* base = xs + oh * 58 + ow;
            float s = 0.f;
#pragma unroll
            for (int kh = 0; kh < 3; kh++)
#pragma unroll
                for (int kw = 0; kw < 3; kw++)
                    s = fmaf(base[kh * 58 + kw], w[kh * 3 + kw], s);
            float val = fmaxf(fmaf(s, inv, sh), 0.f);
            vals[k] = val;
            mx = fmaxf(mx, val);
        }
    }

    __shared__ float red[256];
    red[tid] = mx;
    __syncthreads();
    for (int off = 128; off > 0; off >>= 1) {
        if (tid < off) red[tid] = fmaxf(red[tid], red[tid + off]);
        __syncthreads();
    }
    const float bmax = red[0];
    const int survive = (bmax >= DW_THR) ? 1 : 0;
    if (tid == 0) flags[blk] = survive;
    if (survive) {
        __hip_bfloat16* yp = y + (size_t)blk * HW;
#pragma unroll
        for (int k = 0; k < 13; k++) {
            int p = tid + k * 256;
            if (p < HW) yp[p] = __float2bfloat16(vals[k]);
        }
    }
}

// ---------------- Stage 1.5: deterministic per-batch compaction of surviving channels ----------------
__global__ __launch_bounds__(256) void compact_kernel(
    const int* __restrict__ flags, int* __restrict__ lists, int* __restrict__ counts)
{
    const int b = blockIdx.x, tid = threadIdx.x;
    __shared__ int ps[256];
    const int f = flags[b * CIN + tid];
    ps[tid] = f;
    __syncthreads();
    for (int off = 1; off < 256; off <<= 1) {
        int v = 0;
        if (tid >= off) v = ps[tid - off];
        __syncthreads();
        ps[tid] += v;
        __syncthreads();
    }
    if (f) lists[b * CIN + ps[tid] - 1] = tid;
    if (tid == 255) counts[b] = ps[255];
}

// ---------------- Stage 2: sparse-K pointwise GEMM + BN2 + ReLU + prune ----------------
__global__ __launch_bounds__(256) void pw_kernel(
    const __hip_bfloat16* __restrict__ y,
    const float* __restrict__ pw_w, const float* __restrict__ pw_b,
    const float* __restrict__ g2, const float* __restrict__ b2,
    const float* __restrict__ m2, const float* __restrict__ v2,
    const int* __restrict__ lists, const int* __restrict__ counts,
    float* __restrict__ out)
{
    const int blk = blockIdx.x;
    const int b   = blk >> 6;            // COUT/OT = 64 o-tiles per batch
    const int o0  = (blk & 63) * OT;
    const int tid = threadIdx.x;

    __shared__ int   lst[256];
    __shared__ float wsm[256][OT];       // folded weights, 8 KB
    __shared__ float cterm[OT];
    __shared__ float omax[OT];
    __shared__ float red[256];

    const int K = counts[b];
    for (int i = tid; i < K; i += 256) lst[i] = lists[b * CIN + i];
    if (tid < OT) {
        const int o = o0 + tid;
        const float inv = g2[o] * rsqrtf(v2[o] + EPSV);
        cterm[tid] = (pw_b[o] - m2[o]) * inv + b2[o];
    }
    __syncthreads();
    for (int i = tid; i < K * OT; i += 256) {
        int ck = i / OT, o = i - ck * OT;
        const float inv = g2[o0 + o] * rsqrtf(v2[o0 + o] + EPSV);
        wsm[ck][o] = pw_w[(size_t)(o0 + o) * CIN + lst[ck]] * inv;
    }
    __syncthreads();

    float mloc[OT];
#pragma unroll
    for (int o = 0; o < OT; o++) mloc[o] = 0.f;

    const __hip_bfloat16* yb = y + (size_t)b * CIN * HW;
    float* ob = out + ((size_t)b * COUT + o0) * HW;

    for (int hw0 = 0; hw0 < HW; hw0 += 256) {
        const int hw = hw0 + tid;
        if (hw < HW) {
            float acc[OT];
#pragma unroll
            for (int o = 0; o < OT; o++) acc[o] = cterm[o];
            for (int ck = 0; ck < K; ck++) {
                const float yv = __bfloat162float(yb[(size_t)lst[ck] * HW + hw]);
                const float4 wa = *(const float4*)(&wsm[ck][0]);
                const float4 wb = *(const float4*)(&wsm[ck][4]);
                acc[0] = fmaf(yv, wa.x, acc[0]);
                acc[1] = fmaf(yv, wa.y, acc[1]);
                acc[2] = fmaf(yv, wa.z, acc[2]);
                acc[3] = fmaf(yv, wa.w, acc[3]);
                acc[4] = fmaf(yv, wb.x, acc[4]);
                acc[5] = fmaf(yv, wb.y, acc[5]);
                acc[6] = fmaf(yv, wb.z, acc[6]);
                acc[7] = fmaf(yv, wb.w, acc[7]);
            }
#pragma unroll
            for (int o = 0; o < OT; o++) {
                const float z = fmaxf(acc[o], 0.f);
                ob[(size_t)o * HW + hw] = z;
                mloc[o] = fmaxf(mloc[o], z);
            }
        }
    }

    // per-(b,o) map max for the pointwise prune (each block owns full maps)
    for (int o = 0; o < OT; o++) {
        red[tid] = mloc[o];
        __syncthreads();
        for (int off = 128; off > 0; off >>= 1) {
            if (tid < off) red[tid] = fmaxf(red[tid], red[tid + off]);
            __syncthreads();
        }
        if (tid == 0) omax[o] = red[0];
        __syncthreads();
    }
    for (int o = 0; o < OT; o++) {
        if (omax[o] < PW_THR) {
            for (int hw = tid; hw < HW; hw += 256) ob[(size_t)o * HW + hw] = 0.f;
        }
    }
}

extern "C" void kernel_launch(void* const* d_in, const int* in_sizes, int n_in,
                              void* d_out, int out_size, void* d_ws, size_t ws_size,
                              hipStream_t stream)
{
    const float* x    = (const float*)d_in[0];
    const float* dw_w = (const float*)d_in[1];
    const float* dw_b = (const float*)d_in[2];
    const float* g1   = (const float*)d_in[3];
    const float* b1   = (const float*)d_in[4];
    const float* m1   = (const float*)d_in[5];
    const float* v1   = (const float*)d_in[6];
    const float* pw_w = (const float*)d_in[7];
    const float* pw_b = (const float*)d_in[8];
    const float* g2   = (const float*)d_in[9];
    const float* b2   = (const float*)d_in[10];
    const float* m2   = (const float*)d_in[11];
    const float* v2   = (const float*)d_in[12];
    float* out = (float*)d_out;

    char* ws = (char*)d_ws;
    __hip_bfloat16* y = (__hip_bfloat16*)ws;
    size_t off = (size_t)BB * CIN * HW * sizeof(__hip_bfloat16);  // 51,380,224 B
    int* flags  = (int*)(ws + off); off += (size_t)BB * CIN * 4;
    int* lists  = (int*)(ws + off); off += (size_t)BB * CIN * 4;
    int* counts = (int*)(ws + off); off += (size_t)BB * 4;

    dw_kernel<<<BB * CIN, 256, 0, stream>>>(x, dw_w, dw_b, g1, b1, m1, v1, y, flags);
    compact_kernel<<<BB, 256, 0, stream>>>(flags, lists, counts);
    pw_kernel<<<BB * (COUT / OT), 256, 0, stream>>>(y, pw_w, pw_b, g2, b2, m2, v2, lists, counts, out);
}

// Round 2
// 239.318 us; speedup vs baseline: 1.2204x; 1.2204x over previous
//
#include <hip/hip_runtime.h>
#include <hip/hip_bf16.h>

#define EPSV 1e-5f
#define DW_THR 4.0f
#define PW_THR 1e-3f

static constexpr int BB = 32, CIN = 256, COUT = 512, HH = 56, WW = 56, HW = HH * WW; // 3136
static constexpr int OT = 16; // output channels per block in pointwise stage

// ---------------- Stage 1: depthwise 3x3 + bias + BN1 + ReLU + prune decision ----------------
__global__ __launch_bounds__(256) void dw_kernel(
    const float* __restrict__ x, const float* __restrict__ dw_w, const float* __restrict__ dw_b,
    const float* __restrict__ g1, const float* __restrict__ b1,
    const float* __restrict__ m1, const float* __restrict__ v1,
    __hip_bfloat16* __restrict__ y, int* __restrict__ flags)
{
    const int blk = blockIdx.x;          // b*CIN + c
    const int c   = blk & (CIN - 1);
    const int tid = threadIdx.x;

    __shared__ float xs[58 * 58];        // 56x56 + halo of zeros
    const float* xp = x + (size_t)blk * HW;
    for (int i = tid; i < 58 * 58; i += 256) {
        int r = i / 58, q = i - r * 58;
        int ih = r - 1, iw = q - 1;
        float v = 0.f;
        if ((unsigned)ih < 56u && (unsigned)iw < 56u) v = xp[ih * WW + iw];
        xs[i] = v;
    }

    float w[9];
#pragma unroll
    for (int k = 0; k < 9; k++) w[k] = dw_w[c * 9 + k];
    const float inv = g1[c] * rsqrtf(v1[c] + EPSV);
    const float sh  = (dw_b[c] - m1[c]) * inv + b1[c];
    __syncthreads();

    float vals[13];
    float mx = 0.f;
#pragma unroll
    for (int k = 0; k < 13; k++) {
        int p = tid + k * 256;
        if (p < HW) {
            int oh = p / WW, ow = p - oh * WW;
            const float* base = xs + oh * 58 + ow;
            float s = 0.f;
#pragma unroll
            for (int kh = 0; kh < 3; kh++)
#pragma unroll
                for (int kw = 0; kw < 3; kw++)
                    s = fmaf(base[kh * 58 + kw], w[kh * 3 + kw], s);
            float val = fmaxf(fmaf(s, inv, sh), 0.f);
            vals[k] = val;
            mx = fmaxf(mx, val);
        }
    }

    // wave shuffle reduce then cross-wave
    for (int off = 32; off > 0; off >>= 1) mx = fmaxf(mx, __shfl_xor(mx, off));
    __shared__ float redw[4];
    if ((tid & 63) == 0) redw[tid >> 6] = mx;
    __syncthreads();
    const float bmax = fmaxf(fmaxf(redw[0], redw[1]), fmaxf(redw[2], redw[3]));
    const int survive = (bmax >= DW_THR) ? 1 : 0;
    if (tid == 0) flags[blk] = survive;
    if (survive) {
        __hip_bfloat16* yp = y + (size_t)blk * HW;
#pragma unroll
        for (int k = 0; k < 13; k++) {
            int p = tid + k * 256;
            if (p < HW) yp[p] = __float2bfloat16(vals[k]);
        }
    }
}

// ---------------- Stage 1.5: deterministic per-batch compaction of surviving channels ----------------
__global__ __launch_bounds__(256) void compact_kernel(
    const int* __restrict__ flags, int* __restrict__ lists, int* __restrict__ counts)
{
    const int b = blockIdx.x, tid = threadIdx.x;
    __shared__ int ps[256];
    const int f = flags[b * CIN + tid];
    ps[tid] = f;
    __syncthreads();
    for (int off = 1; off < 256; off <<= 1) {
        int v = 0;
        if (tid >= off) v = ps[tid - off];
        __syncthreads();
        ps[tid] += v;
        __syncthreads();
    }
    if (f) lists[b * CIN + ps[tid] - 1] = tid;
    if (tid == 255) counts[b] = ps[255];
}

// ---------------- Stage 2: sparse-K pointwise GEMM + BN2 + ReLU + prune ----------------
// One block per (batch, 16-output-channel tile). Each thread: 4 consecutive pixels.
__global__ __launch_bounds__(256) void pw_kernel(
    const __hip_bfloat16* __restrict__ y,
    const float* __restrict__ pw_w, const float* __restrict__ pw_b,
    const float* __restrict__ g2, const float* __restrict__ b2,
    const float* __restrict__ m2, const float* __restrict__ v2,
    const int* __restrict__ lists, const int* __restrict__ counts,
    float* __restrict__ out)
{
    const int blk = blockIdx.x;
    const int b   = blk >> 5;            // COUT/OT = 32 o-tiles per batch
    const int o0  = (blk & 31) * OT;
    const int tid = threadIdx.x;

    __shared__ int   lst[256];
    __shared__ float wsm[256][OT];       // folded weights (16 KB max)
    __shared__ float cterm[OT];
    __shared__ float omax[OT];
    __shared__ float redw[4][OT];

    const int K = counts[b];
    for (int i = tid; i < K; i += 256) lst[i] = lists[b * CIN + i];
    if (tid < OT) {
        const int o = o0 + tid;
        const float inv = g2[o] * rsqrtf(v2[o] + EPSV);
        cterm[tid] = (pw_b[o] - m2[o]) * inv + b2[o];
    }
    __syncthreads();
    for (int i = tid; i < K * OT; i += 256) {
        int ck = i >> 4, o = i & (OT - 1);
        const float inv = g2[o0 + o] * rsqrtf(v2[o0 + o] + EPSV);
        wsm[ck][o] = pw_w[(size_t)(o0 + o) * CIN + lst[ck]] * inv;
    }
    __syncthreads();

    float mloc[OT];
#pragma unroll
    for (int o = 0; o < OT; o++) mloc[o] = 0.f;

    const __hip_bfloat16* yb = y + (size_t)b * CIN * HW;
    float* ob = out + ((size_t)b * COUT + o0) * HW;

    for (int chunk = 0; chunk < 4; chunk++) {
        const int p = chunk * 1024 + tid * 4;
        if (p < HW) {
            float acc[OT][4];
#pragma unroll
            for (int o = 0; o < OT; o++) {
                const float c = cterm[o];
                acc[o][0] = c; acc[o][1] = c; acc[o][2] = c; acc[o][3] = c;
            }
            int ck = 0;
            for (; ck + 2 <= K; ck += 2) {
                const ushort4 ya = *(const ushort4*)(yb + (size_t)lst[ck] * HW + p);
                const ushort4 yc = *(const ushort4*)(yb + (size_t)lst[ck + 1] * HW + p);
                float fa[4], fc[4];
                fa[0] = __bfloat162float(*(const __hip_bfloat16*)&ya.x);
                fa[1] = __bfloat162float(*(const __hip_bfloat16*)&ya.y);
                fa[2] = __bfloat162float(*(const __hip_bfloat16*)&ya.z);
                fa[3] = __bfloat162float(*(const __hip_bfloat16*)&ya.w);
                fc[0] = __bfloat162float(*(const __hip_bfloat16*)&yc.x);
                fc[1] = __bfloat162float(*(const __hip_bfloat16*)&yc.y);
                fc[2] = __bfloat162float(*(const __hip_bfloat16*)&yc.z);
                fc[3] = __bfloat162float(*(const __hip_bfloat16*)&yc.w);
#pragma unroll
                for (int o = 0; o < OT; o++) {
                    const float w0 = wsm[ck][o], w1 = wsm[ck + 1][o];
#pragma unroll
                    for (int q = 0; q < 4; q++) {
                        acc[o][q] = fmaf(fa[q], w0, acc[o][q]);
                        acc[o][q] = fmaf(fc[q], w1, acc[o][q]);
                    }
                }
            }
            if (ck < K) {
                const ushort4 ya = *(const ushort4*)(yb + (size_t)lst[ck] * HW + p);
                float fa[4];
                fa[0] = __bfloat162float(*(const __hip_bfloat16*)&ya.x);
                fa[1] = __bfloat162float(*(const __hip_bfloat16*)&ya.y);
                fa[2] = __bfloat162float(*(const __hip_bfloat16*)&ya.z);
                fa[3] = __bfloat162float(*(const __hip_bfloat16*)&ya.w);
#pragma unroll
                for (int o = 0; o < OT; o++) {
                    const float w0 = wsm[ck][o];
#pragma unroll
                    for (int q = 0; q < 4; q++) acc[o][q] = fmaf(fa[q], w0, acc[o][q]);
                }
            }
#pragma unroll
            for (int o = 0; o < OT; o++) {
                float4 z;
                z.x = fmaxf(acc[o][0], 0.f);
                z.y = fmaxf(acc[o][1], 0.f);
                z.z = fmaxf(acc[o][2], 0.f);
                z.w = fmaxf(acc[o][3], 0.f);
                *(float4*)(ob + (size_t)o * HW + p) = z;
                mloc[o] = fmaxf(mloc[o], fmaxf(fmaxf(z.x, z.y), fmaxf(z.z, z.w)));
            }
        }
    }

    // per-(b,o) map max for the pointwise prune: wave shuffle + cross-wave
#pragma unroll
    for (int o = 0; o < OT; o++)
        for (int off = 32; off > 0; off >>= 1) mloc[o] = fmaxf(mloc[o], __shfl_xor(mloc[o], off));
    const int wid = tid >> 6;
    if ((tid & 63) == 0) {
#pragma unroll
        for (int o = 0; o < OT; o++) redw[wid][o] = mloc[o];
    }
    __syncthreads();
    if (tid < OT) {
        omax[tid] = fmaxf(fmaxf(redw[0][tid], redw[1][tid]),
                          fmaxf(redw[2][tid], redw[3][tid]));
    }
    __syncthreads();
    for (int o = 0; o < OT; o++) {
        if (omax[o] < PW_THR) {
            for (int hw = tid; hw < HW; hw += 256) ob[(size_t)o * HW + hw] = 0.f;
        }
    }
}

extern "C" void kernel_launch(void* const* d_in, const int* in_sizes, int n_in,
                              void* d_out, int out_size, void* d_ws, size_t ws_size,
                              hipStream_t stream)
{
    const float* x    = (const float*)d_in[0];
    const float* dw_w = (const float*)d_in[1];
    const float* dw_b = (const float*)d_in[2];
    const float* g1   = (const float*)d_in[3];
    const float* b1   = (const float*)d_in[4];
    const float* m1   = (const float*)d_in[5];
    const float* v1   = (const float*)d_in[6];
    const float* pw_w = (const float*)d_in[7];
    const float* pw_b = (const float*)d_in[8];
    const float* g2   = (const float*)d_in[9];
    const float* b2   = (const float*)d_in[10];
    const float* m2   = (const float*)d_in[11];
    const float* v2   = (const float*)d_in[12];
    float* out = (float*)d_out;

    char* ws = (char*)d_ws;
    __hip_bfloat16* y = (__hip_bfloat16*)ws;
    size_t off = (size_t)BB * CIN * HW * sizeof(__hip_bfloat16);  // 51,380,224 B
    int* flags  = (int*)(ws + off); off += (size_t)BB * CIN * 4;
    int* lists  = (int*)(ws + off); off += (size_t)BB * CIN * 4;
    int* counts = (int*)(ws + off); off += (size_t)BB * 4;

    dw_kernel<<<BB * CIN, 256, 0, stream>>>(x, dw_w, dw_b, g1, b1, m1, v1, y, flags);
    compact_kernel<<<BB, 256, 0, stream>>>(flags, lists, counts);
    pw_kernel<<<BB * (COUT / OT), 256, 0, stream>>>(y, pw_w, pw_b, g2, b2, m2, v2, lists, counts, out);
}

// Round 3
// 206.835 us; speedup vs baseline: 1.4121x; 1.1570x over previous
//
#include <hip/hip_runtime.h>
#include <hip/hip_bf16.h>

#define EPSV 1e-5f
#define DW_THR 4.0f
#define PW_THR 1e-3f

static constexpr int BB = 32, CIN = 256, COUT = 512, HH = 56, WW = 56, HW = HH * WW; // 3136

typedef __attribute__((ext_vector_type(8))) short bf16x8;
typedef __attribute__((ext_vector_type(4))) float f32x4;

// ---------------- Stage 1: depthwise 3x3 + bias + BN1 + ReLU + prune decision ----------------
__global__ __launch_bounds__(256) void dw_kernel(
    const float* __restrict__ x, const float* __restrict__ dw_w, const float* __restrict__ dw_b,
    const float* __restrict__ g1, const float* __restrict__ b1,
    const float* __restrict__ m1, const float* __restrict__ v1,
    __hip_bfloat16* __restrict__ y, int* __restrict__ flags)
{
    const int blk = blockIdx.x;          // b*CIN + c
    const int c   = blk & (CIN - 1);
    const int tid = threadIdx.x;

    __shared__ float xs[58 * 58];        // 56x56 + halo of zeros
    const float* xp = x + (size_t)blk * HW;
    for (int i = tid; i < 58 * 58; i += 256) {
        int r = i / 58, q = i - r * 58;
        int ih = r - 1, iw = q - 1;
        float v = 0.f;
        if ((unsigned)ih < 56u && (unsigned)iw < 56u) v = xp[ih * WW + iw];
        xs[i] = v;
    }

    float w[9];
#pragma unroll
    for (int k = 0; k < 9; k++) w[k] = dw_w[c * 9 + k];
    const float inv = g1[c] * rsqrtf(v1[c] + EPSV);
    const float sh  = (dw_b[c] - m1[c]) * inv + b1[c];
    __syncthreads();

    float vals[13];
    float mx = 0.f;
#pragma unroll
    for (int k = 0; k < 13; k++) {
        int p = tid + k * 256;
        if (p < HW) {
            int oh = p / WW, ow = p - oh * WW;
            const float* base = xs + oh * 58 + ow;
            float s = 0.f;
#pragma unroll
            for (int kh = 0; kh < 3; kh++)
#pragma unroll
                for (int kw = 0; kw < 3; kw++)
                    s = fmaf(base[kh * 58 + kw], w[kh * 3 + kw], s);
            float val = fmaxf(fmaf(s, inv, sh), 0.f);
            vals[k] = val;
            mx = fmaxf(mx, val);
        }
    }

    for (int off = 32; off > 0; off >>= 1) mx = fmaxf(mx, __shfl_xor(mx, off));
    __shared__ float redw[4];
    if ((tid & 63) == 0) redw[tid >> 6] = mx;
    __syncthreads();
    const float bmax = fmaxf(fmaxf(redw[0], redw[1]), fmaxf(redw[2], redw[3]));
    const int survive = (bmax >= DW_THR) ? 1 : 0;
    if (tid == 0) flags[blk] = survive;
    if (survive) {
        __hip_bfloat16* yp = y + (size_t)blk * HW;
#pragma unroll
        for (int k = 0; k < 13; k++) {
            int p = tid + k * 256;
            if (p < HW) yp[p] = __float2bfloat16(vals[k]);
        }
    }
}

// ---------------- fold BN2 into pointwise weights (bf16) + constant term ----------------
__global__ __launch_bounds__(256) void fold_kernel(
    const float* __restrict__ pw_w, const float* __restrict__ pw_b,
    const float* __restrict__ g2, const float* __restrict__ b2,
    const float* __restrict__ m2, const float* __restrict__ v2,
    __hip_bfloat16* __restrict__ Wf, float* __restrict__ cterm)
{
    const int o = blockIdx.x, t = threadIdx.x;
    const float inv = g2[o] * rsqrtf(v2[o] + EPSV);
    Wf[o * CIN + t] = __float2bfloat16(pw_w[o * CIN + t] * inv);
    if (t == 0) cterm[o] = (pw_b[o] - m2[o]) * inv + b2[o];
}

// ---------------- transpose y[b][c][n] -> yT[b][n][c], zeroing pruned channels ----------------
// tile: 64 channels x 64 pixels; 3136 = 49*64 exactly
__global__ __launch_bounds__(256) void transpose_kernel(
    const __hip_bfloat16* __restrict__ y, const int* __restrict__ flags,
    __hip_bfloat16* __restrict__ yT)
{
    const int blk = blockIdx.x;
    const int nt = blk % 49;
    const int rem = blk / 49;
    const int ct = rem & 3;
    const int b  = rem >> 2;
    const int t = threadIdx.x;

    __shared__ unsigned short ts[64][68]; // +4 pad
    __shared__ int fl[64];
    if (t < 64) fl[t] = flags[b * CIN + ct * 64 + t];
    __syncthreads();

    const unsigned short* yp = (const unsigned short*)y + ((size_t)b * CIN + ct * 64) * HW + nt * 64;
#pragma unroll
    for (int k = 0; k < 4; k++) {
        int u = t + k * 256;
        int row = u >> 4, cu = u & 15;   // 16 ushort4-units per 64-px row
        ushort4 v = make_ushort4(0, 0, 0, 0);
        if (fl[row]) v = *(const ushort4*)(yp + (size_t)row * HW + cu * 4);
        *(ushort4*)(&ts[row][cu * 4]) = v;
    }
    __syncthreads();

    unsigned short* yTp = (unsigned short*)yT + ((size_t)b * HW + (size_t)nt * 64) * CIN + ct * 64;
#pragma unroll
    for (int k = 0; k < 4; k++) {
        int u = t + k * 256;
        int n = u >> 4, cc = u & 15;
        ushort4 v;
        v.x = ts[cc * 4 + 0][n];
        v.y = ts[cc * 4 + 1][n];
        v.z = ts[cc * 4 + 2][n];
        v.w = ts[cc * 4 + 3][n];
        *(ushort4*)(yTp + (size_t)n * CIN + cc * 4) = v;
    }
}

// ---------------- Stage 2: dense bf16 MFMA GEMM per batch + BN2 + ReLU + partial max ----------------
// block tile 128(o) x 128(n), 4 waves 2x2, wave tile 64x64; K = 256 dense
__global__ __launch_bounds__(256) void gemm_kernel(
    const __hip_bfloat16* __restrict__ Wf_, const __hip_bfloat16* __restrict__ yT_,
    const float* __restrict__ cterm, float* __restrict__ out, float* __restrict__ pmax)
{
    const int blk = blockIdx.x;
    const int b = blk / 100;
    const int rem = blk % 100;
    const int mt = rem / 25, nt = rem % 25;
    const int tid = threadIdx.x, l = tid & 63, wid = tid >> 6;
    const int wm = wid >> 1, wn = wid & 1;
    const int o_base = mt * 128 + wm * 64;
    const int n_base = nt * 128 + wn * 64;
    const int lr = l & 15, lk = l >> 4;

    const short* W = (const short*)Wf_;
    const short* Y = (const short*)yT_ + (size_t)b * HW * CIN;

    f32x4 acc[4][4];
#pragma unroll
    for (int mr = 0; mr < 4; mr++)
#pragma unroll
        for (int nr = 0; nr < 4; nr++) acc[mr][nr] = (f32x4){0.f, 0.f, 0.f, 0.f};

    for (int k0 = 0; k0 < CIN; k0 += 32) {
        bf16x8 a[4], bf[4];
#pragma unroll
        for (int mr = 0; mr < 4; mr++)
            a[mr] = *(const bf16x8*)(W + (size_t)(o_base + mr * 16 + lr) * CIN + k0 + lk * 8);
#pragma unroll
        for (int nr = 0; nr < 4; nr++)
            bf[nr] = *(const bf16x8*)(Y + (size_t)(n_base + nr * 16 + lr) * CIN + k0 + lk * 8);
#pragma unroll
        for (int mr = 0; mr < 4; mr++)
#pragma unroll
            for (int nr = 0; nr < 4; nr++)
                acc[mr][nr] = __builtin_amdgcn_mfma_f32_16x16x32_bf16(a[mr], bf[nr], acc[mr][nr], 0, 0, 0);
    }

    // epilogue: + cterm, ReLU, store, per-o partial max
    float ct[4][4], om[4][4];
#pragma unroll
    for (int mr = 0; mr < 4; mr++)
#pragma unroll
        for (int rg = 0; rg < 4; rg++) {
            ct[mr][rg] = cterm[o_base + mr * 16 + lk * 4 + rg];
            om[mr][rg] = 0.f;
        }
#pragma unroll
    for (int mr = 0; mr < 4; mr++) {
#pragma unroll
        for (int nr = 0; nr < 4; nr++) {
            const int n = n_base + nr * 16 + lr;
#pragma unroll
            for (int rg = 0; rg < 4; rg++) {
                const int o = o_base + mr * 16 + lk * 4 + rg;
                float v = fmaxf(acc[mr][nr][rg] + ct[mr][rg], 0.f);
                if (n < HW) {
                    out[((size_t)b * COUT + o) * HW + n] = v;
                    om[mr][rg] = fmaxf(om[mr][rg], v);
                }
            }
        }
    }
#pragma unroll
    for (int d = 1; d < 16; d <<= 1)
#pragma unroll
        for (int mr = 0; mr < 4; mr++)
#pragma unroll
            for (int rg = 0; rg < 4; rg++)
                om[mr][rg] = fmaxf(om[mr][rg], __shfl_xor(om[mr][rg], d));
    if (lr == 0) {
#pragma unroll
        for (int mr = 0; mr < 4; mr++)
#pragma unroll
            for (int rg = 0; rg < 4; rg++) {
                const int o = o_base + mr * 16 + lk * 4 + rg;
                pmax[(size_t)(b * COUT + o) * 25 + nt] = om[mr][rg];
            }
    }
}

// ---------------- pointwise prune fixup (rare) ----------------
__global__ __launch_bounds__(64) void fixup_kernel(const float* __restrict__ pmax, float* __restrict__ out)
{
    const int blk = blockIdx.x;
    const int b = blk >> 9, o = blk & 511;
    const int t = threadIdx.x;
    float m = (t < 25) ? pmax[(size_t)(b * COUT + o) * 25 + t] : 0.f;
#pragma unroll
    for (int d = 1; d < 64; d <<= 1) m = fmaxf(m, __shfl_xor(m, d));
    if (m < PW_THR) {
        float* p = out + ((size_t)b * COUT + o) * HW;
        for (int n = t; n < HW; n += 64) p[n] = 0.f;
    }
}

extern "C" void kernel_launch(void* const* d_in, const int* in_sizes, int n_in,
                              void* d_out, int out_size, void* d_ws, size_t ws_size,
                              hipStream_t stream)
{
    const float* x    = (const float*)d_in[0];
    const float* dw_w = (const float*)d_in[1];
    const float* dw_b = (const float*)d_in[2];
    const float* g1   = (const float*)d_in[3];
    const float* b1   = (const float*)d_in[4];
    const float* m1   = (const float*)d_in[5];
    const float* v1   = (const float*)d_in[6];
    const float* pw_w = (const float*)d_in[7];
    const float* pw_b = (const float*)d_in[8];
    const float* g2   = (const float*)d_in[9];
    const float* b2   = (const float*)d_in[10];
    const float* m2   = (const float*)d_in[11];
    const float* v2   = (const float*)d_in[12];
    float* out = (float*)d_out;

    char* ws = (char*)d_ws;
    size_t off = 0;
    __hip_bfloat16* y  = (__hip_bfloat16*)(ws + off); off += (size_t)BB * CIN * HW * 2;          // 51,380,224
    __hip_bfloat16* yT = (__hip_bfloat16*)(ws + off); off += (size_t)BB * HW * CIN * 2 + 32768;  // +tail pad for OOB frag reads
    int*   flags = (int*)(ws + off);   off += (size_t)BB * CIN * 4;
    __hip_bfloat16* Wf = (__hip_bfloat16*)(ws + off); off += (size_t)COUT * CIN * 2;
    float* cterm = (float*)(ws + off); off += (size_t)COUT * 4;
    float* pmax  = (float*)(ws + off); off += (size_t)BB * COUT * 25 * 4;

    fold_kernel<<<COUT, CIN, 0, stream>>>(pw_w, pw_b, g2, b2, m2, v2, Wf, cterm);
    dw_kernel<<<BB * CIN, 256, 0, stream>>>(x, dw_w, dw_b, g1, b1, m1, v1, y, flags);
    transpose_kernel<<<BB * 4 * 49, 256, 0, stream>>>(y, flags, yT);
    gemm_kernel<<<BB * 4 * 25, 256, 0, stream>>>(Wf, yT, cterm, out, pmax);
    fixup_kernel<<<BB * COUT, 64, 0, stream>>>(pmax, out);
}

// Round 5
// 152.274 us; speedup vs baseline: 1.9180x; 1.3583x over previous
//
#include <hip/hip_runtime.h>
#include <hip/hip_bf16.h>

#define EPSV 1e-5f
#define DW_THR 4.0f
#define PW_THR 1e-3f

static constexpr int BB = 32, CIN = 256, COUT = 512, HH = 56, WW = 56, HW = HH * WW; // 3136

typedef __attribute__((ext_vector_type(8))) short bf16x8;
typedef __attribute__((ext_vector_type(4))) float f32x4;

__device__ __forceinline__ void glds16(const void* g, void* l) {
    __builtin_amdgcn_global_load_lds((const __attribute__((address_space(1))) void*)g,
                                     (__attribute__((address_space(3))) void*)l, 16, 0, 0);
}

// ---------------- Stage 1: depthwise 3x3 + bias + BN1 + ReLU + prune decision ----------------
__global__ __launch_bounds__(256) void dw_kernel(
    const float* __restrict__ x, const float* __restrict__ dw_w, const float* __restrict__ dw_b,
    const float* __restrict__ g1, const float* __restrict__ b1,
    const float* __restrict__ m1, const float* __restrict__ v1,
    __hip_bfloat16* __restrict__ y, int* __restrict__ flags)
{
    const int blk = blockIdx.x;          // b*CIN + c
    const int c   = blk & (CIN - 1);
    const int tid = threadIdx.x;

    __shared__ float xs[58 * 58];
    const float* xp = x + (size_t)blk * HW;
    for (int i = tid; i < 58 * 58; i += 256) {
        int r = i / 58, q = i - r * 58;
        int ih = r - 1, iw = q - 1;
        float v = 0.f;
        if ((unsigned)ih < 56u && (unsigned)iw < 56u) v = xp[ih * WW + iw];
        xs[i] = v;
    }

    float w[9];
#pragma unroll
    for (int k = 0; k < 9; k++) w[k] = dw_w[c * 9 + k];
    const float inv = g1[c] * rsqrtf(v1[c] + EPSV);
    const float sh  = (dw_b[c] - m1[c]) * inv + b1[c];
    __syncthreads();

    float vals[13];
    float mx = 0.f;
#pragma unroll
    for (int k = 0; k < 13; k++) {
        int p = tid + k * 256;
        if (p < HW) {
            int oh = p / WW, ow = p - oh * WW;
            const float* base = xs + oh * 58 + ow;
            float s = 0.f;
#pragma unroll
            for (int kh = 0; kh < 3; kh++)
#pragma unroll
                for (int kw = 0; kw < 3; kw++)
                    s = fmaf(base[kh * 58 + kw], w[kh * 3 + kw], s);
            float val = fmaxf(fmaf(s, inv, sh), 0.f);
            vals[k] = val;
            mx = fmaxf(mx, val);
        }
    }

    for (int off = 32; off > 0; off >>= 1) mx = fmaxf(mx, __shfl_xor(mx, off));
    __shared__ float redw[4];
    if ((tid & 63) == 0) redw[tid >> 6] = mx;
    __syncthreads();
    const float bmax = fmaxf(fmaxf(redw[0], redw[1]), fmaxf(redw[2], redw[3]));
    const int survive = (bmax >= DW_THR) ? 1 : 0;
    if (tid == 0) flags[blk] = survive;
    if (survive) {
        __hip_bfloat16* yp = y + (size_t)blk * HW;
#pragma unroll
        for (int k = 0; k < 13; k++) {
            int p = tid + k * 256;
            if (p < HW) yp[p] = __float2bfloat16(vals[k]);
        }
    }
}

// ---------------- fold BN2 into pointwise weights (bf16) + constant term ----------------
__global__ __launch_bounds__(256) void fold_kernel(
    const float* __restrict__ pw_w, const float* __restrict__ pw_b,
    const float* __restrict__ g2, const float* __restrict__ b2,
    const float* __restrict__ m2, const float* __restrict__ v2,
    __hip_bfloat16* __restrict__ Wf, float* __restrict__ cterm)
{
    const int o = blockIdx.x, t = threadIdx.x;
    const float inv = g2[o] * rsqrtf(v2[o] + EPSV);
    Wf[o * CIN + t] = __float2bfloat16(pw_w[o * CIN + t] * inv);
    if (t == 0) cterm[o] = (pw_b[o] - m2[o]) * inv + b2[o];
}

// ---------------- transpose y[b][c][n] -> yT[b][n][c], zeroing pruned channels (VERIFIED R2) ----------------
__global__ __launch_bounds__(256) void transpose_kernel(
    const __hip_bfloat16* __restrict__ y, const int* __restrict__ flags,
    __hip_bfloat16* __restrict__ yT)
{
    const int blk = blockIdx.x;
    const int nt = blk % 49;
    const int rem = blk / 49;
    const int ct = rem & 3;
    const int b  = rem >> 2;
    const int t = threadIdx.x;

    __shared__ unsigned short ts[64][68]; // +4 pad
    __shared__ int fl[64];
    if (t < 64) fl[t] = flags[b * CIN + ct * 64 + t];
    __syncthreads();

    const unsigned short* yp = (const unsigned short*)y + ((size_t)b * CIN + ct * 64) * HW + nt * 64;
#pragma unroll
    for (int k = 0; k < 4; k++) {
        int u = t + k * 256;
        int row = u >> 4, cu = u & 15;
        ushort4 v = make_ushort4(0, 0, 0, 0);
        if (fl[row]) v = *(const ushort4*)(yp + (size_t)row * HW + cu * 4);
        *(ushort4*)(&ts[row][cu * 4]) = v;
    }
    __syncthreads();

    unsigned short* yTp = (unsigned short*)yT + ((size_t)b * HW + (size_t)nt * 64) * CIN + ct * 64;
#pragma unroll
    for (int k = 0; k < 4; k++) {
        int u = t + k * 256;
        int n = u >> 4, cc = u & 15;
        ushort4 v;
        v.x = ts[cc * 4 + 0][n];
        v.y = ts[cc * 4 + 1][n];
        v.z = ts[cc * 4 + 2][n];
        v.w = ts[cc * 4 + 3][n];
        *(ushort4*)(yTp + (size_t)n * CIN + cc * 4) = v;
    }
}

// ---------------- Stage 2: LDS-staged dense bf16 MFMA GEMM + BN2 + ReLU + partial max ----------------
// block tile 128(o) x 128(n), 4 waves 2x2, wave tile 64x64; K = 256, BK = 32
__global__ __launch_bounds__(256) void gemm_kernel(
    const __hip_bfloat16* __restrict__ Wf_, const __hip_bfloat16* __restrict__ yT_,
    const float* __restrict__ cterm, float* __restrict__ out, float* __restrict__ pmax)
{
    // XCD-bijective swizzle: 3200 = 8 * 400 -> each XCD gets 4 whole batches (yT-batch L2-resident)
    const int orig = blockIdx.x;
    const int blk  = (orig & 7) * 400 + (orig >> 3);
    const int b    = blk / 100;
    const int rem  = blk % 100;
    const int mt = rem / 25, nt = rem % 25;
    const int tid = threadIdx.x, l = tid & 63, wid = tid >> 6;
    const int wm = wid >> 1, wn = wid & 1;
    const int lr = l & 15, lk = l >> 4;
    const int o0 = mt * 128, n0 = nt * 128;

    __shared__ unsigned short Al[128 * 32];  // 8 KB: row r, 4 slots x 8k; slot s holds k-chunk s^((r>>1)&3)
    __shared__ unsigned short Bl[128 * 32];  // 8 KB: same layout over n-rows

    const short* W = (const short*)Wf_;
    const short* Y = (const short*)yT_ + (size_t)b * HW * CIN;

    // staging sources: lane l -> rowInChunk = l>>2, slot = l&3, src k-chunk = (l&3)^((l>>3)&3)
    const int kch   = (((l & 3) ^ ((l >> 3) & 3)) << 3);
    const int rowA  = o0 + 32 * wid + (l >> 2);
    const short* asrc0 = W + (size_t)rowA * CIN + kch;
    const short* asrc1 = W + (size_t)(rowA + 16) * CIN + kch;
    const int rowB  = n0 + 32 * wid + (l >> 2);
    const short* bsrc0 = Y + (size_t)rowB * CIN + kch;
    const short* bsrc1 = Y + (size_t)(rowB + 16) * CIN + kch;

    f32x4 acc[4][4];
#pragma unroll
    for (int mr = 0; mr < 4; mr++)
#pragma unroll
        for (int nr = 0; nr < 4; nr++) acc[mr][nr] = (f32x4){0.f, 0.f, 0.f, 0.f};

#pragma unroll
    for (int t = 0; t < 8; t++) {
        const int k0 = t * 32;
        glds16(asrc0 + k0, (void*)(&Al[(2 * wid) * 512]));
        glds16(asrc1 + k0, (void*)(&Al[(2 * wid + 1) * 512]));
        glds16(bsrc0 + k0, (void*)(&Bl[(2 * wid) * 512]));
        glds16(bsrc1 + k0, (void*)(&Bl[(2 * wid + 1) * 512]));
        __syncthreads();   // compiler drains vmcnt before barrier (m97 pattern)

        bf16x8 a[4], bb[4];
#pragma unroll
        for (int mr = 0; mr < 4; mr++) {
            const int r = wm * 64 + mr * 16 + lr;
            a[mr] = *(const bf16x8*)((const char*)Al + r * 64 + ((lk ^ ((r >> 1) & 3)) << 4));
        }
#pragma unroll
        for (int nr = 0; nr < 4; nr++) {
            const int r = wn * 64 + nr * 16 + lr;
            bb[nr] = *(const bf16x8*)((const char*)Bl + r * 64 + ((lk ^ ((r >> 1) & 3)) << 4));
        }
#pragma unroll
        for (int nr = 0; nr < 4; nr++)
#pragma unroll
            for (int mr = 0; mr < 4; mr++)
                acc[mr][nr] = __builtin_amdgcn_mfma_f32_16x16x32_bf16(a[mr], bb[nr], acc[mr][nr], 0, 0, 0);
        __syncthreads();
    }

    // ---- epilogue: + cterm, ReLU, store, per-o partial max (VERIFIED R2 conventions) ----
    float ct[4][4], om[4][4];
#pragma unroll
    for (int mr = 0; mr < 4; mr++)
#pragma unroll
        for (int rg = 0; rg < 4; rg++) {
            ct[mr][rg] = cterm[o0 + wm * 64 + mr * 16 + lk * 4 + rg];
            om[mr][rg] = 0.f;
        }
#pragma unroll
    for (int mr = 0; mr < 4; mr++) {
#pragma unroll
        for (int nr = 0; nr < 4; nr++) {
            const int n = n0 + wn * 64 + nr * 16 + lr;
#pragma unroll
            for (int rg = 0; rg < 4; rg++) {
                const int o = o0 + wm * 64 + mr * 16 + lk * 4 + rg;
                float v = fmaxf(acc[mr][nr][rg] + ct[mr][rg], 0.f);
                if (n < HW) {
                    out[((size_t)b * COUT + o) * HW + n] = v;
                    om[mr][rg] = fmaxf(om[mr][rg], v);
                }
            }
        }
    }
#pragma unroll
    for (int d = 1; d < 16; d <<= 1)
#pragma unroll
        for (int mr = 0; mr < 4; mr++)
#pragma unroll
            for (int rg = 0; rg < 4; rg++)
                om[mr][rg] = fmaxf(om[mr][rg], __shfl_xor(om[mr][rg], d));
    if (lr == 0) {
#pragma unroll
        for (int mr = 0; mr < 4; mr++)
#pragma unroll
            for (int rg = 0; rg < 4; rg++) {
                const int o = o0 + wm * 64 + mr * 16 + lk * 4 + rg;
                pmax[(size_t)(b * COUT + o) * 25 + nt] = om[mr][rg];
            }
    }
}

// ---------------- pointwise prune fixup (rare) ----------------
__global__ __launch_bounds__(64) void fixup_kernel(const float* __restrict__ pmax, float* __restrict__ out)
{
    const int blk = blockIdx.x;
    const int b = blk >> 9, o = blk & 511;
    const int t = threadIdx.x;
    float m = (t < 25) ? pmax[(size_t)(b * COUT + o) * 25 + t] : 0.f;
#pragma unroll
    for (int d = 1; d < 64; d <<= 1) m = fmaxf(m, __shfl_xor(m, d));
    if (m < PW_THR) {
        float* p = out + ((size_t)b * COUT + o) * HW;
        for (int n = t; n < HW; n += 64) p[n] = 0.f;
    }
}

extern "C" void kernel_launch(void* const* d_in, const int* in_sizes, int n_in,
                              void* d_out, int out_size, void* d_ws, size_t ws_size,
                              hipStream_t stream)
{
    const float* x    = (const float*)d_in[0];
    const float* dw_w = (const float*)d_in[1];
    const float* dw_b = (const float*)d_in[2];
    const float* g1   = (const float*)d_in[3];
    const float* b1   = (const float*)d_in[4];
    const float* m1   = (const float*)d_in[5];
    const float* v1   = (const float*)d_in[6];
    const float* pw_w = (const float*)d_in[7];
    const float* pw_b = (const float*)d_in[8];
    const float* g2   = (const float*)d_in[9];
    const float* b2   = (const float*)d_in[10];
    const float* m2   = (const float*)d_in[11];
    const float* v2   = (const float*)d_in[12];
    float* out = (float*)d_out;

    char* ws = (char*)d_ws;
    size_t off = 0;
    __hip_bfloat16* y  = (__hip_bfloat16*)(ws + off); off += (size_t)BB * CIN * HW * 2;          // 51,380,224
    __hip_bfloat16* yT = (__hip_bfloat16*)(ws + off); off += (size_t)BB * HW * CIN * 2 + 65536;  // + tail pad (OOB n-tile staging)
    int*   flags = (int*)(ws + off);   off += (size_t)BB * CIN * 4;
    __hip_bfloat16* Wf = (__hip_bfloat16*)(ws + off); off += (size_t)COUT * CIN * 2;
    float* cterm = (float*)(ws + off); off += (size_t)COUT * 4;
    float* pmax  = (float*)(ws + off); off += (size_t)BB * COUT * 25 * 4;

    fold_kernel<<<COUT, CIN, 0, stream>>>(pw_w, pw_b, g2, b2, m2, v2, Wf, cterm);
    dw_kernel<<<BB * CIN, 256, 0, stream>>>(x, dw_w, dw_b, g1, b1, m1, v1, y, flags);
    transpose_kernel<<<BB * 4 * 49, 256, 0, stream>>>(y, flags, yT);
    gemm_kernel<<<BB * 4 * 25, 256, 0, stream>>>(Wf, yT, cterm, out, pmax);
    fixup_kernel<<<BB * COUT, 64, 0, stream>>>(pmax, out);
}